// Round 1
// baseline (253.300 us; speedup 1.0000x reference)
//
#include <hip/hip_runtime.h>

#define NUM_CLASSES 21
#define HW (512 * 512)
#define BATCH 8
#define GRIDX 128           // blocks per image along pixel dim
#define BLOCK 256
#define PIX_PER_BLOCK (HW / GRIDX)   // 2048 -> 8 pixels/thread

// ws layout (floats): [0 .. 167] union[b][c], [168 .. 335] intersect[b][c]
#define WS_FLOATS (2 * BATCH * NUM_CLASSES)

__global__ void zero_ws_kernel(float* ws) {
    int i = blockIdx.x * blockDim.x + threadIdx.x;
    if (i < WS_FLOATS) ws[i] = 0.0f;
}

__global__ __launch_bounds__(BLOCK) void iou_partial_kernel(
        const float* __restrict__ in,   // [B, C, H, W]
        const int* __restrict__ tgt,    // [B, H, W]
        float* __restrict__ ws) {
    const int b = blockIdx.y;
    __shared__ float s_union[NUM_CLASSES];
    __shared__ float s_inter[NUM_CLASSES];
    if (threadIdx.x < NUM_CLASSES) {
        s_union[threadIdx.x] = 0.0f;
        s_inter[threadIdx.x] = 0.0f;
    }
    __syncthreads();

    const float* inb = in + (size_t)b * NUM_CLASSES * HW;
    const int*   tb  = tgt + (size_t)b * HW;
    const int start = blockIdx.x * PIX_PER_BLOCK;

    for (int p = start + threadIdx.x; p < start + PIX_PER_BLOCK; p += BLOCK) {
        const int t = tb[p];
        float v[NUM_CLASSES];
        #pragma unroll
        for (int c = 0; c < NUM_CLASSES; ++c)
            v[c] = inb[(size_t)c * HW + p];

        // argmax (first index on tie, matching jnp.argmax) + target value
        float m = v[0];
        int   am = 0;
        float vt = v[0];
        #pragma unroll
        for (int c = 1; c < NUM_CLASSES; ++c) {
            if (v[c] > m) { m = v[c]; am = c; }
        }
        #pragma unroll
        for (int c = 1; c < NUM_CLASSES; ++c)
            vt = (c == t) ? v[c] : vt;

        float s = 0.0f;
        #pragma unroll
        for (int c = 0; c < NUM_CLASSES; ++c)
            s += __expf(v[c] - m);
        const float inv    = 1.0f / s;     // p_pred = exp(m-m)/s = 1/s
        const float p_pred = inv;
        const float p_t    = __expf(vt - m) * inv;

        atomicAdd(&s_union[am], p_pred);
        if (am == t) {
            atomicAdd(&s_inter[am], p_pred);   // union mask clamps 2 -> 1: only one union add
        } else {
            atomicAdd(&s_union[t], p_t);
        }
    }
    __syncthreads();

    if (threadIdx.x < NUM_CLASSES) {
        atomicAdd(&ws[b * NUM_CLASSES + threadIdx.x], s_union[threadIdx.x]);
        atomicAdd(&ws[BATCH * NUM_CLASSES + b * NUM_CLASSES + threadIdx.x],
                  s_inter[threadIdx.x]);
    }
}

__global__ __launch_bounds__(BLOCK) void finalize_kernel(
        const float* __restrict__ ws, float* __restrict__ out) {
    __shared__ float red[BLOCK];
    const int i = threadIdx.x;
    float val = 0.0f;
    if (i < BATCH * NUM_CLASSES) {
        const float u  = ws[i];
        const float it = ws[BATCH * NUM_CLASSES + i];
        const float ratio = it / fmaxf(u, 1.0f);
        const float d = ratio - 1.0f;
        val = d * d;
    }
    red[i] = val;
    __syncthreads();
    for (int off = BLOCK / 2; off > 0; off >>= 1) {
        if (i < off) red[i] += red[i + off];
        __syncthreads();
    }
    if (i == 0) out[0] = red[0] / (float)BATCH;
}

extern "C" void kernel_launch(void* const* d_in, const int* in_sizes, int n_in,
                              void* d_out, int out_size, void* d_ws, size_t ws_size,
                              hipStream_t stream) {
    const float* in  = (const float*)d_in[0];
    const int*   tgt = (const int*)d_in[1];
    float* ws  = (float*)d_ws;
    float* out = (float*)d_out;

    zero_ws_kernel<<<1, 512, 0, stream>>>(ws);
    dim3 grid(GRIDX, BATCH);
    iou_partial_kernel<<<grid, BLOCK, 0, stream>>>(in, tgt, ws);
    finalize_kernel<<<1, BLOCK, 0, stream>>>(ws, out);
}